// Round 1
// baseline (839.682 us; speedup 1.0000x reference)
//
#include <hip/hip_runtime.h>

#define T_DIM 2048
#define B_DIM 96
#define C_DIM 128
#define L_DIM 128
#define S_DIM 257              // 2L+1
#define NEGF (-1e30f)
#define LOG2E 1.4426950408889634f
#define LN2 0.69314718055994531f
#define SMOOTH 0.1f
#define PF 8

// Blocks 0..95: CTC alpha recursion, one sample per block, 256 threads.
//   thread i owns extended-label state s = i+1 (1..256); lane 0 additionally
//   carries s=0 (pure-blank state: alpha0 += lp_blank, no logsumexp needed).
//   Alphas kept in log2 domain so v_exp_f32/v_log_f32 are used raw.
// Blocks 96..191: KL partial sums (sum over t<Tb, c!=0 of log_probs[t,b,c]).
__global__ __launch_bounds__(256) void ctc_fused_kernel(
    const float* __restrict__ lp, const int* __restrict__ targets,
    const int* __restrict__ in_len, const int* __restrict__ tg_len,
    float* __restrict__ ws)
{
  const int tid = threadIdx.x;
  const int blk = blockIdx.x;
  if (blk < B_DIM) {
    // ---------------- CTC recursion ----------------
    // abuf[buf][s+2] holds alpha[s]; slots [0],[1] are a permanent NEG halo.
    __shared__ float abuf[2][S_DIM + 2];
    const int b = blk;
    const int s = tid + 1;               // owned state, 1..256
    const int Tb = in_len[b];

    int ext_s = 0;                       // BLANK for even s
    bool can_skip = false;
    if (s & 1) {
      const int idx = (s - 1) >> 1;
      ext_s = targets[b * L_DIM + idx];
      can_skip = (s >= 3) && (ext_s != targets[b * L_DIM + idx - 1]);
    }

    const size_t stride = (size_t)B_DIM * C_DIM;     // floats per t-row
    const float* gp = lp + (size_t)b * C_DIM + ext_s;

    // t = 0 init (log2 domain)
    const float lp00 = gp[0];
    float a = (s <= 1) ? lp00 * LOG2E : NEGF;
    // lane 1 of wave 0 owns s=2 (blank) -> its gather IS lp[t][blank]
    float a0 = __shfl(lp00, 1, 64) * LOG2E;          // only tid 0 uses

    if (tid < 2) { abuf[0][tid] = NEGF; abuf[1][tid] = NEGF; }
    abuf[0][s + 2] = a;
    if (tid == 0) abuf[0][2] = a0;
    __syncthreads();

    // software prefetch ring, statically indexed (unroll-by-PF)
    float pf[PF];
    #pragma unroll
    for (int k = 0; k < PF; ++k) pf[k] = gp[(size_t)(k + 1) * stride];

    int prev = 0;
    for (int tt = 1; tt < T_DIM; tt += PF) {
      #pragma unroll
      for (int k = 0; k < PF; ++k) {
        const int t = tt + k;
        if (t < T_DIM) {                 // uniform across block
          float lpv = pf[k] * LOG2E;
          if (t + PF < T_DIM) pf[k] = gp[(size_t)(t + PF) * stride];
          const float lpb = __shfl(lpv, 1, 64);      // blank lp (wave0 lane1)
          const float a1  = abuf[prev][s + 1];       // alpha[s-1]
          const float a2r = abuf[prev][s];           // alpha[s-2]
          const float a2  = can_skip ? a2r : NEGF;
          const float m   = fmaxf(fmaxf(a, a1), a2);
          const float e0  = __builtin_amdgcn_exp2f(a  - m);
          const float e1  = __builtin_amdgcn_exp2f(a1 - m);
          const float e2  = __builtin_amdgcn_exp2f(a2 - m);
          const float anew = m + __builtin_amdgcn_logf(e0 + e1 + e2) + lpv;
          const bool active = (t < Tb);
          a = active ? anew : a;
          const int cur = prev ^ 1;
          abuf[cur][s + 2] = a;
          if (tid == 0) {
            a0 = active ? (a0 + lpb) : a0;           // s=0: alpha += lp_blank
            abuf[cur][2] = a0;
          }
          prev = cur;
          __syncthreads();
        }
      }
    }

    if (tid == 0) {
      const int Lt = tg_len[b];
      const float x = abuf[prev][2 * Lt + 2];        // alpha[2L]
      const float y = abuf[prev][2 * Lt + 1];        // alpha[2L-1]
      const float mm = fmaxf(x, y);
      const float ll2 = mm + __builtin_amdgcn_logf(
          __builtin_amdgcn_exp2f(x - mm) + __builtin_amdgcn_exp2f(y - mm));
      const float ll = ll2 * LN2;                    // back to ln domain
      ws[b] = (ll < NEGF * 0.5f) ? 0.0f : -ll;       // zero_infinity
    }
  } else {
    // ---------------- KL partial sums ----------------
    const int b = blk - B_DIM;
    if (b >= B_DIM) return;
    const int Tb = in_len[b];
    const int rl  = tid >> 5;            // 8 rows per iteration
    const int l32 = tid & 31;            // 32 threads x float4 = 128 floats/row
    float acc = 0.0f;
    for (int t = rl; t < Tb; t += 8) {
      const float4 v = *(const float4*)(lp + ((size_t)t * B_DIM + b) * C_DIM + l32 * 4);
      float ssum = v.x + v.y + v.z + v.w;
      if (l32 == 0) ssum -= v.x;         // exclude blank c=0
      acc += ssum;
    }
    __shared__ float red[256];
    red[tid] = acc;
    __syncthreads();
    for (int off = 128; off > 0; off >>= 1) {
      if (tid < off) red[tid] += red[tid + off];
      __syncthreads();
    }
    if (tid == 0) ws[B_DIM + b] = red[0];
  }
}

__global__ __launch_bounds__(128) void ctc_finalize_kernel(
    const float* __restrict__ ws, const int* __restrict__ in_len,
    float* __restrict__ out)
{
  __shared__ float red[128];
  const int tid = threadIdx.x;
  float v = 0.0f;
  if (tid < B_DIM) {
    const float ctc  = ws[tid];
    const float kls  = ws[B_DIM + tid];
    const float u    = 1.0f / (C_DIM - 1);
    const float logu = -4.8441870864585910f;         // log(1/127)
    const float klmean = logu - u * kls / (float)in_len[tid];
    v = (1.0f - SMOOTH) * ctc + SMOOTH * klmean;
  }
  red[tid] = v;
  __syncthreads();
  for (int off = 64; off > 0; off >>= 1) {
    if (tid < off) red[tid] += red[tid + off];
    __syncthreads();
  }
  if (tid == 0) out[0] = red[0] / (float)B_DIM;
}

extern "C" void kernel_launch(void* const* d_in, const int* in_sizes, int n_in,
                              void* d_out, int out_size, void* d_ws, size_t ws_size,
                              hipStream_t stream) {
  const float* lp      = (const float*)d_in[0];
  const int* targets   = (const int*)d_in[1];
  const int* in_len    = (const int*)d_in[2];
  const int* tg_len    = (const int*)d_in[3];
  float* ws  = (float*)d_ws;
  float* out = (float*)d_out;

  hipLaunchKernelGGL(ctc_fused_kernel, dim3(2 * B_DIM), dim3(256), 0, stream,
                     lp, targets, in_len, tg_len, ws);
  hipLaunchKernelGGL(ctc_finalize_kernel, dim3(1), dim3(128), 0, stream,
                     ws, in_len, out);
}

// Round 6
// 566.346 us; speedup vs baseline: 1.4826x; 1.4826x over previous
//
#include <hip/hip_runtime.h>
#include <math.h>

#define T_DIM 2048
#define B_DIM 96
#define C_DIM 128
#define L_DIM 128
#define LOG2E 1.4426950408889634f
#define LN2 0.69314718055994531f
#define SMOOTH 0.1f
#define RING 16
#define SENT (-(1 << 30))
#define NEGL (-3.0e38f)

// wave shift-right-by-1, 0-fill form — IDENTICAL to the R1-proven helper.
// (lane 0's result is overridden explicitly by the caller.)
__device__ __forceinline__ float dpp_shr1_f(float x) {
  return __int_as_float(__builtin_amdgcn_update_dpp(
      0, __float_as_int(x), 0x138 /*WAVE_SR1*/, 0xF, 0xF, true));
}

// One block (256 thr) per sample b.
//   wave 0  : CTC alpha recursion, linear domain, per-lane int frame E
//             (true = stored * 2^E). Lane l owns states s=4l..4l+3 in
//             r0..r3 (+ r4 dup of s=4l+4). The ONLY cross-lane traffic is
//             x3 = log2(r3)+E as one float via DPP. Receiver adopts frames
//             with downward-only ldexp scaling; d3=exp2(clamped) can never
//             overflow. Registers recentered to 2^60 every step.
//   waves1-3: KL partial sum  sum_{t<Tb, c!=0} lp[t][b][c].
__global__ __launch_bounds__(256) void ctc_fused_kernel(
    const float* __restrict__ lp, const int* __restrict__ targets,
    const int* __restrict__ in_len, const int* __restrict__ tg_len,
    float* __restrict__ ws)
{
  const int tid = threadIdx.x;
  const int b = blockIdx.x;
  const size_t RSTR = (size_t)B_DIM * C_DIM;     // floats per t-row
  const int Tb = in_len[b];
  const float* base = lp + (size_t)b * C_DIM;

  __shared__ float als[257];
  __shared__ float klred[3];

  if (tid < 64) {
    // ---------------- CTC (wave 0) ----------------
    const int l = tid;
    const int tgA = targets[b * L_DIM + 2 * l];
    const int tgB = targets[b * L_DIM + 2 * l + 1];
    const float skA = (l > 0 && tgA != targets[b * L_DIM + 2 * l - 1]) ? 1.f : 0.f;
    const float skB = (tgB != tgA) ? 1.f : 0.f;

    float r0 = 0.f, r1 = 0.f, r2 = 0.f, r3 = 0.f, r4 = 0.f;
    int E = SENT;
    if (l == 0) {
      r0 = __builtin_amdgcn_exp2f(base[0]   * LOG2E);
      r1 = __builtin_amdgcn_exp2f(base[tgA] * LOG2E);
      E = 0;
    }
    float Ef = (float)E;           // float(SENT) = -2^30 exactly (pow2)
    float x3 = NEGL;               // log2(alpha[4l+3]) absolute; r3=0 at t=0

    float gA[RING], gB[RING], gK[RING];
    #pragma unroll
    for (int k = 0; k < RING; ++k) {
      const float* rw = base + (size_t)(k + 1) * RSTR;
      gA[k] = rw[tgA]; gB[k] = rw[tgB]; gK[k] = rw[0];
    }
    const float* rowPF = base + (size_t)(RING + 1) * RSTR;

    for (int t0 = 1; t0 < Tb; t0 += RING) {
      #pragma unroll
      for (int k = 0; k < RING; ++k) {
        const int t = t0 + k;
        if (t < Tb) {                              // wave-uniform guard
          const float lpA = gA[k], lpB = gB[k], lpK = gK[k];
          gA[k] = rowPF[tgA]; gB[k] = rowPF[tgB]; gK[k] = rowPF[0];
          if (t + RING + 1 < T_DIM) rowPF += RSTR;

          const float pA = __builtin_amdgcn_exp2f(lpA * LOG2E);
          const float pB = __builtin_amdgcn_exp2f(lpB * LOG2E);
          const float pK = __builtin_amdgcn_exp2f(lpK * LOG2E);

          // ---- boundary: absolute-log2 float via proven DPP ----
          float d3l = dpp_shr1_f(x3);
          d3l = (l == 0) ? NEGL : d3l;             // no inflow to lane 0

          // frame adoption: if incoming exceeds frame top 2^(E+60),
          // raise E and scale own regs DOWN (sh>=0 -> never overflows).
          const float diff = d3l - Ef - 60.0f;
          const int sh = (diff > 0.0f) ? ((int)diff + 1) : 0;
          r0 = ldexpf(r0, -sh); r1 = ldexpf(r1, -sh); r2 = ldexpf(r2, -sh);
          r3 = ldexpf(r3, -sh); r4 = ldexpf(r4, -sh);
          E += sh; Ef = (float)E;

          const float d3 = __builtin_amdgcn_exp2f(fminf(d3l - Ef, 124.0f));

          const float n0 = (r0 + d3) * pK;                         // s=4l   blank
          const float n1 = __builtin_fmaf(skA, d3, r0 + r1) * pA;  // s=4l+1 label
          const float n2 = (r2 + r1) * pK;                         // s=4l+2 blank
          const float n3 = __builtin_fmaf(skB, r1, r3 + r2) * pB;  // s=4l+3 label
          const float n4 = (r4 + r3) * pK;                         // s=4l+4 blank

          // export next step's boundary value (frame-neutral wrt recenter)
          x3 = __builtin_amdgcn_logf(n3) + Ef;     // log2; n3=0 -> -inf (safe)

          // per-lane recenter to 2^60 EVERY step (values <= 2^125 here)
          const float m = fmaxf(fmaxf(fmaxf(n0, n1), fmaxf(n2, n3)), n4);
          int sh2 = 0;
          if (m > 0.0f) sh2 = 187 - ((__float_as_int(m) >> 23) & 0xFF);
          r0 = ldexpf(n0, sh2); r1 = ldexpf(n1, sh2); r2 = ldexpf(n2, sh2);
          r3 = ldexpf(n3, sh2); r4 = ldexpf(n4, sh2);
          E -= sh2; Ef = (float)E;
        }
      }
    }

    als[4 * l + 0] = __builtin_amdgcn_logf(r0) + Ef;
    als[4 * l + 1] = __builtin_amdgcn_logf(r1) + Ef;
    als[4 * l + 2] = __builtin_amdgcn_logf(r2) + Ef;
    als[4 * l + 3] = __builtin_amdgcn_logf(r3) + Ef;
    if (l == 63) als[256] = __builtin_amdgcn_logf(r4) + Ef;
  } else {
    // ---------------- KL (waves 1..3) ----------------
    const int idx = tid - 64;                      // 0..191
    const int rr  = idx >> 5;                      // 6 rows per sweep
    const int c4  = (idx & 31) * 4;
    float a0 = 0.f, a1 = 0.f, a2 = 0.f, a3 = 0.f;
    for (int t0 = 0; t0 < Tb; t0 += 48) {
      #pragma unroll
      for (int j = 0; j < 8; ++j) {
        const int t = t0 + 6 * j + rr;
        if (t < Tb) {
          const float4 v = *(const float4*)(base + (size_t)t * RSTR + c4);
          float s = v.x + v.y + v.z + v.w;
          if (c4 == 0) s -= v.x;                   // exclude blank c=0
          if ((j & 3) == 0) a0 += s;
          else if ((j & 3) == 1) a1 += s;
          else if ((j & 3) == 2) a2 += s;
          else a3 += s;
        }
      }
    }
    float tot = (a0 + a1) + (a2 + a3);
    tot += __shfl_xor(tot, 1, 64);
    tot += __shfl_xor(tot, 2, 64);
    tot += __shfl_xor(tot, 4, 64);
    tot += __shfl_xor(tot, 8, 64);
    tot += __shfl_xor(tot, 16, 64);
    tot += __shfl_xor(tot, 32, 64);
    if ((tid & 63) == 0) klred[(tid >> 6) - 1] = tot;
  }
  __syncthreads();
  if (tid == 0) {
    const int Lt = tg_len[b];
    const float xa = als[2 * Lt], xb = als[2 * Lt - 1];  // log2 domain
    const float mm = fmaxf(xa, xb);
    float loss = 0.f;
    if (mm > -1e30f) {
      loss = -((mm + __builtin_amdgcn_logf(
          __builtin_amdgcn_exp2f(xa - mm) + __builtin_amdgcn_exp2f(xb - mm))) * LN2);
    }
    ws[b] = loss;                                  // zero_infinity: loss 0
    ws[B_DIM + b] = klred[0] + klred[1] + klred[2];
  }
}

__global__ __launch_bounds__(128) void ctc_finalize_kernel(
    const float* __restrict__ ws, const int* __restrict__ in_len,
    float* __restrict__ out)
{
  __shared__ float red[128];
  const int tid = threadIdx.x;
  float v = 0.0f;
  if (tid < B_DIM) {
    const float ctc  = ws[tid];
    const float kls  = ws[B_DIM + tid];
    const float u    = 1.0f / (C_DIM - 1);
    const float logu = -4.8441870864585910f;       // log(1/127)
    const float klmean = logu - u * kls / (float)in_len[tid];
    v = (1.0f - SMOOTH) * ctc + SMOOTH * klmean;
  }
  red[tid] = v;
  __syncthreads();
  for (int off = 64; off > 0; off >>= 1) {
    if (tid < off) red[tid] += red[tid + off];
    __syncthreads();
  }
  if (tid == 0) out[0] = red[0] / (float)B_DIM;
}

extern "C" void kernel_launch(void* const* d_in, const int* in_sizes, int n_in,
                              void* d_out, int out_size, void* d_ws, size_t ws_size,
                              hipStream_t stream) {
  const float* lp      = (const float*)d_in[0];
  const int* targets   = (const int*)d_in[1];
  const int* in_len    = (const int*)d_in[2];
  const int* tg_len    = (const int*)d_in[3];
  float* ws  = (float*)d_ws;
  float* out = (float*)d_out;

  hipLaunchKernelGGL(ctc_fused_kernel, dim3(B_DIM), dim3(256), 0, stream,
                     lp, targets, in_len, tg_len, ws);
  hipLaunchKernelGGL(ctc_finalize_kernel, dim3(1), dim3(128), 0, stream,
                     ws, in_len, out);
}

// Round 7
// 299.806 us; speedup vs baseline: 2.8008x; 1.8890x over previous
//
#include <hip/hip_runtime.h>
#include <math.h>

#define T_DIM 2048
#define B_DIM 96
#define C_DIM 128
#define L_DIM 128
#define LOG2E 1.4426950408889634f
#define LN2 0.69314718055994531f
#define SMOOTH 0.1f
#define SENT (-(1 << 30))
#define NEGL (-3.0e38f)
#define NPH 64                  // 64 phases x 32 steps cover t = 1..2047

// wave shift-right-by-1, 0-fill (R1/R6-proven helper); lane 0 overridden.
__device__ __forceinline__ float dpp_shr1_f(float x) {
  return __int_as_float(__builtin_amdgcn_update_dpp(
      0, __float_as_int(x), 0x138 /*WAVE_SR1*/, 0xF, 0xF, true));
}

// One block (256 thr) per sample b.
//   wave 0   (consumer): CTC alpha recursion — R6's proven math, fed from LDS.
//   waves1-3 (producer): stream rows t of lp[.,b,.] coalesced; write each
//                        512B row into a triple-buffered LDS ring 2 phases
//                        ahead; accumulate the KL sum from the same loads.
__global__ __launch_bounds__(256) void ctc_fused_kernel(
    const float* __restrict__ lp, const int* __restrict__ targets,
    const int* __restrict__ in_len, const int* __restrict__ tg_len,
    float* __restrict__ ws)
{
  const int tid = threadIdx.x;
  const int b = blockIdx.x;
  const size_t RSTR = (size_t)B_DIM * C_DIM;       // floats per t-row
  const int Tb = in_len[b];
  const float* base = lp + (size_t)b * C_DIM;

  __shared__ float rows[3][32][C_DIM];             // 48 KB ring
  __shared__ float als[257];
  __shared__ float klred[3];

  // consumer state (wave 0 only)
  int tgA = 0, tgB = 0;
  float skA = 0.f, skB = 0.f;
  float r0 = 0.f, r1 = 0.f, r2 = 0.f, r3 = 0.f, r4 = 0.f;
  int E = SENT; float Ef = (float)SENT;
  float x3 = NEGL;
  float cA = 0.f, cB = 0.f, cK = 0.f;
  float klacc = 0.f;                               // producers only

  if (tid < 64) {
    // ---- consumer setup + t=0 init (global, once) ----
    const int l = tid;
    tgA = targets[b * L_DIM + 2 * l];
    tgB = targets[b * L_DIM + 2 * l + 1];
    skA = (l > 0 && tgA != targets[b * L_DIM + 2 * l - 1]) ? 1.f : 0.f;
    skB = (tgB != tgA) ? 1.f : 0.f;
    if (l == 0) {
      r0 = __builtin_amdgcn_exp2f(base[0]   * LOG2E);
      r1 = __builtin_amdgcn_exp2f(base[tgA] * LOG2E);
      E = 0;
    }
    Ef = (float)E;
  } else {
    // ---- prefill: rows t=1..64 -> buf0,buf1; plus row-0 KL ----
    const int ptid = tid - 64;                     // 0..191
    #pragma unroll
    for (int i = 0; i < 11; ++i) {
      const int task = i * 192 + ptid;             // 64 rows x 32 float4
      if (task < 2048) {
        const int row = task >> 5;                 // 0..63 ; t = 1+row
        const int c4  = task & 31;
        const int t   = 1 + row;
        const float4 v = *(const float4*)(base + (size_t)t * RSTR + c4 * 4);
        *(float4*)&rows[row >> 5][row & 31][c4 * 4] = v;
        if (t < Tb) {
          float s = v.x + v.y + v.z + v.w;
          if (c4 == 0) s -= v.x;                   // exclude blank c=0
          klacc += s;
        }
      }
    }
    if (ptid < 32 && 0 < Tb) {                     // row 0 KL contribution
      const float4 v = *(const float4*)(base + ptid * 4);
      float s = v.x + v.y + v.z + v.w;
      if (ptid == 0) s -= v.x;
      klacc += s;
    }
  }
  __syncthreads();

  if (tid < 64) {                                  // first step's lp from LDS
    cA = rows[0][0][tgA]; cB = rows[0][0][tgB]; cK = rows[0][0][0];
  }

  float* pc = &rows[0][0][0];                      // consumer: current phase
  float* pn = &rows[1][0][0];                      // next phase (complete)
  float* pf = &rows[2][0][0];                      // producer fill target

  for (int p = 0; p < NPH; ++p) {
    if (tid < 64) {
      // ---------------- consumer: 32 steps ----------------
      const int l = tid;
      #pragma unroll
      for (int k = 0; k < 32; ++k) {
        const int t = 1 + 32 * p + k;
        if (t < Tb) {                              // wave-uniform guard
          // prefetch next step's lp from LDS (k=31 -> next buffer row 0)
          const float* nr = (k < 31) ? (pc + (k + 1) * C_DIM) : pn;
          const float nA = nr[tgA], nB = nr[tgB], nK = nr[0];

          const float pAv = __builtin_amdgcn_exp2f(cA * LOG2E);
          const float pBv = __builtin_amdgcn_exp2f(cB * LOG2E);
          const float pKv = __builtin_amdgcn_exp2f(cK * LOG2E);

          // boundary: absolute-log2 float via proven DPP
          float d3l = dpp_shr1_f(x3);
          d3l = (l == 0) ? NEGL : d3l;

          // frame adoption: downward-only scaling (overflow impossible)
          const float diff = d3l - Ef - 60.0f;
          const int sh = (diff > 0.0f) ? ((int)diff + 1) : 0;
          r0 = ldexpf(r0, -sh); r1 = ldexpf(r1, -sh); r2 = ldexpf(r2, -sh);
          r3 = ldexpf(r3, -sh); r4 = ldexpf(r4, -sh);
          E += sh; Ef = (float)E;

          const float d3 = __builtin_amdgcn_exp2f(fminf(d3l - Ef, 124.0f));

          const float n0 = (r0 + d3) * pKv;                         // blank
          const float n1 = __builtin_fmaf(skA, d3, r0 + r1) * pAv;  // label
          const float n2 = (r2 + r1) * pKv;                         // blank
          const float n3 = __builtin_fmaf(skB, r1, r3 + r2) * pBv;  // label
          const float n4 = (r4 + r3) * pKv;                         // blank

          x3 = __builtin_amdgcn_logf(n3) + Ef;     // export (frame-neutral)

          // per-lane recenter to 2^60 every step
          const float m = fmaxf(fmaxf(fmaxf(n0, n1), fmaxf(n2, n3)), n4);
          int sh2 = 0;
          if (m > 0.0f) sh2 = 187 - ((__float_as_int(m) >> 23) & 0xFF);
          r0 = ldexpf(n0, sh2); r1 = ldexpf(n1, sh2); r2 = ldexpf(n2, sh2);
          r3 = ldexpf(n3, sh2); r4 = ldexpf(n4, sh2);
          E -= sh2; Ef = (float)E;

          cA = nA; cB = nB; cK = nK;
        }
      }
    } else {
      // ---------------- producers: fill phase p+2 ----------------
      const int ptid = tid - 64;
      const int t0 = 65 + 32 * p;
      if (t0 < T_DIM) {
        #pragma unroll
        for (int i = 0; i < 6; ++i) {
          const int task = i * 192 + ptid;         // 32 rows x 32 float4
          if (task < 1024) {
            const int row = task >> 5;
            const int c4  = task & 31;
            const int t   = t0 + row;
            if (t < T_DIM) {
              const float4 v = *(const float4*)(base + (size_t)t * RSTR + c4 * 4);
              *(float4*)&pf[row * C_DIM + c4 * 4] = v;
              if (t < Tb) {
                float s = v.x + v.y + v.z + v.w;
                if (c4 == 0) s -= v.x;
                klacc += s;
              }
            }
          }
        }
      }
    }
    __syncthreads();
    float* tmp = pc; pc = pn; pn = pf; pf = tmp;   // rotate ring
  }

  // ---------------- epilogue ----------------
  if (tid < 64) {
    const int l = tid;
    als[4 * l + 0] = __builtin_amdgcn_logf(r0) + Ef;
    als[4 * l + 1] = __builtin_amdgcn_logf(r1) + Ef;
    als[4 * l + 2] = __builtin_amdgcn_logf(r2) + Ef;
    als[4 * l + 3] = __builtin_amdgcn_logf(r3) + Ef;
    if (l == 63) als[256] = __builtin_amdgcn_logf(r4) + Ef;
  } else {
    float tot = klacc;
    tot += __shfl_xor(tot, 1, 64);
    tot += __shfl_xor(tot, 2, 64);
    tot += __shfl_xor(tot, 4, 64);
    tot += __shfl_xor(tot, 8, 64);
    tot += __shfl_xor(tot, 16, 64);
    tot += __shfl_xor(tot, 32, 64);
    if ((tid & 63) == 0) klred[(tid >> 6) - 1] = tot;
  }
  __syncthreads();
  if (tid == 0) {
    const int Lt = tg_len[b];
    const float xa = als[2 * Lt], xb = als[2 * Lt - 1];  // log2 domain
    const float mm = fmaxf(xa, xb);
    float loss = 0.f;
    if (mm > -1e30f) {
      loss = -((mm + __builtin_amdgcn_logf(
          __builtin_amdgcn_exp2f(xa - mm) + __builtin_amdgcn_exp2f(xb - mm))) * LN2);
    }
    ws[b] = loss;                                  // zero_infinity: loss 0
    ws[B_DIM + b] = klred[0] + klred[1] + klred[2];
  }
}

__global__ __launch_bounds__(128) void ctc_finalize_kernel(
    const float* __restrict__ ws, const int* __restrict__ in_len,
    float* __restrict__ out)
{
  __shared__ float red[128];
  const int tid = threadIdx.x;
  float v = 0.0f;
  if (tid < B_DIM) {
    const float ctc  = ws[tid];
    const float kls  = ws[B_DIM + tid];
    const float u    = 1.0f / (C_DIM - 1);
    const float logu = -4.8441870864585910f;       // log(1/127)
    const float klmean = logu - u * kls / (float)in_len[tid];
    v = (1.0f - SMOOTH) * ctc + SMOOTH * klmean;
  }
  red[tid] = v;
  __syncthreads();
  for (int off = 64; off > 0; off >>= 1) {
    if (tid < off) red[tid] += red[tid + off];
    __syncthreads();
  }
  if (tid == 0) out[0] = red[0] / (float)B_DIM;
}

extern "C" void kernel_launch(void* const* d_in, const int* in_sizes, int n_in,
                              void* d_out, int out_size, void* d_ws, size_t ws_size,
                              hipStream_t stream) {
  const float* lp      = (const float*)d_in[0];
  const int* targets   = (const int*)d_in[1];
  const int* in_len    = (const int*)d_in[2];
  const int* tg_len    = (const int*)d_in[3];
  float* ws  = (float*)d_ws;
  float* out = (float*)d_out;

  hipLaunchKernelGGL(ctc_fused_kernel, dim3(B_DIM), dim3(256), 0, stream,
                     lp, targets, in_len, tg_len, ws);
  hipLaunchKernelGGL(ctc_finalize_kernel, dim3(1), dim3(128), 0, stream,
                     ws, in_len, out);
}

// Round 9
// 254.178 us; speedup vs baseline: 3.3035x; 1.1795x over previous
//
#include <hip/hip_runtime.h>
#include <math.h>

#define T_DIM 2048
#define B_DIM 96
#define C_DIM 128
#define L_DIM 128
#define LOG2E 1.4426950408889634f
#define LN2 0.69314718055994531f
#define SMOOTH 0.1f
#define SENT (-(1 << 30))       // virgin lane frame (f32-exact power of 2)
#define NPH 64                  // 64 phases x 32 steps cover t = 1..2047

// wave shift-right-by-1, 0-fill — the R1/R6/R7-proven helper (float only).
__device__ __forceinline__ float dpp_shr1_f(float x) {
  return __int_as_float(__builtin_amdgcn_update_dpp(
      0, __float_as_int(x), 0x138 /*WAVE_SR1*/, 0xF, 0xF, true));
}

// One block (256 thr) per sample b.
//   wave 0   (consumer): CTC alpha recursion, linear domain, per-lane int
//     frame E (true = stored * 2^E). Boundary: r3 and (float)E cross via the
//     proven float DPP. Receiver adoption is VALUE-driven (integer exponent
//     extraction, gated on r3s != 0) -> no stale-frame deadlock (R4/5/8 bug),
//     no transcendentals, no overflow (all reconciling shifts bounded).
//   waves1-3 (producer): stream rows coalesced, write p=exp2(lp*log2e) into a
//     triple-buffered LDS ring 2 phases ahead; accumulate KL from raw values.
__global__ __launch_bounds__(256) void ctc_fused_kernel(
    const float* __restrict__ lp, const int* __restrict__ targets,
    const int* __restrict__ in_len, const int* __restrict__ tg_len,
    float* __restrict__ ws)
{
  const int tid = threadIdx.x;
  const int b = blockIdx.x;
  const size_t RSTR = (size_t)B_DIM * C_DIM;       // floats per t-row
  const int Tb = in_len[b];
  const float* base = lp + (size_t)b * C_DIM;

  __shared__ float rows[3][32][C_DIM];             // 48 KB ring of PROBS
  __shared__ float als[257];
  __shared__ float klred[3];

  // consumer state
  int tgA = 0, tgB = 0;
  float skA = 0.f, skB = 0.f;
  float r0 = 0.f, r1 = 0.f, r2 = 0.f, r3 = 0.f, r4 = 0.f;
  int E = SENT;
  float fA[4], fB[4], fK[4];                       // depth-4 LDS pipeline
  float klacc = 0.f;                               // producers only

  if (tid < 64) {
    const int l = tid;
    tgA = targets[b * L_DIM + 2 * l];
    tgB = targets[b * L_DIM + 2 * l + 1];
    skA = (l > 0 && tgA != targets[b * L_DIM + 2 * l - 1]) ? 1.f : 0.f;
    skB = (tgB != tgA) ? 1.f : 0.f;
    if (l == 0) {
      r0 = __builtin_amdgcn_exp2f(base[0]   * LOG2E);
      r1 = __builtin_amdgcn_exp2f(base[tgA] * LOG2E);
      E = 0;
    }
  } else {
    // prefill rows t=1..64 (bufs 0,1) as PROBS; KL for t=0..64 from raw
    const int ptid = tid - 64;                     // 0..191
    #pragma unroll
    for (int i = 0; i < 11; ++i) {
      const int task = i * 192 + ptid;             // 64 rows x 32 float4
      if (task < 2048) {
        const int row = task >> 5;
        const int c4  = task & 31;
        const int t   = 1 + row;
        const float4 v = *(const float4*)(base + (size_t)t * RSTR + c4 * 4);
        float4 w;
        w.x = __builtin_amdgcn_exp2f(v.x * LOG2E);
        w.y = __builtin_amdgcn_exp2f(v.y * LOG2E);
        w.z = __builtin_amdgcn_exp2f(v.z * LOG2E);
        w.w = __builtin_amdgcn_exp2f(v.w * LOG2E);
        *(float4*)&rows[row >> 5][row & 31][c4 * 4] = w;
        if (t < Tb) {
          float s = v.x + v.y + v.z + v.w;
          if (c4 == 0) s -= v.x;
          klacc += s;
        }
      }
    }
    if (ptid < 32 && 0 < Tb) {                     // row 0 KL contribution
      const float4 v = *(const float4*)(base + ptid * 4);
      float s = v.x + v.y + v.z + v.w;
      if (ptid == 0) s -= v.x;
      klacc += s;
    }
  }
  __syncthreads();

  if (tid < 64) {                                  // pipeline prologue
    #pragma unroll
    for (int j = 0; j < 4; ++j) {
      fA[j] = rows[0][j][tgA]; fB[j] = rows[0][j][tgB]; fK[j] = rows[0][j][0];
    }
  }

  float* pc = &rows[0][0][0];
  float* pn = &rows[1][0][0];
  float* pf = &rows[2][0][0];

  for (int p = 0; p < NPH; ++p) {
    if (tid < 64) {
      // -------- consumer: 32 steps, zero transcendentals --------
      #pragma unroll
      for (int k = 0; k < 32; ++k) {
        const int t = 1 + 32 * p + k;
        if (t < Tb) {                              // wave-uniform guard
          const float pAv = fA[k & 3], pBv = fB[k & 3], pKv = fK[k & 3];
          {                                        // refill slot with row k+4
            const int kk = k + 4;
            const float* nr = (kk < 32) ? (pc + kk * C_DIM)
                                        : (pn + (kk - 32) * C_DIM);
            fA[k & 3] = nr[tgA]; fB[k & 3] = nr[tgB]; fK[k & 3] = nr[0];
          }

          // ---- boundary: (r3, frame) via proven float DPP ----
          const float r3s = dpp_shr1_f(r3);        // lane0 -> 0
          const int   Es  = (int)dpp_shr1_f((float)E);  // exact; lane0 gated
          const int   be  = (__float_as_int(r3s) >> 23) & 0xFF;
          // VALUE-driven adoption: only when real mass arrives above frame top
          int diff = (be - 187) + (Es - E);        // e_in - (E + 60)
          diff = (__float_as_int(r3s) != 0 && diff > 0) ? diff : 0;
          r0 = ldexpf(r0, -diff); r1 = ldexpf(r1, -diff); r2 = ldexpf(r2, -diff);
          r3 = ldexpf(r3, -diff); r4 = ldexpf(r4, -diff);
          E += diff;
          const float d3 = ldexpf(r3s, Es - E);    // exponent <= 60 by constr.

          const float n0 = (r0 + d3) * pKv;                         // blank
          const float n1 = __builtin_fmaf(skA, d3, r0 + r1) * pAv;  // label
          const float n2 = (r2 + r1) * pKv;                         // blank
          const float n3 = __builtin_fmaf(skB, r1, r3 + r2) * pBv;  // label
          const float n4 = (r4 + r3) * pKv;                         // blank
          r0 = n0; r1 = n1; r2 = n2; r3 = n3; r4 = n4;

          if ((k & 3) == 3) {                      // recenter to 2^60 / 4 steps
            const float m = fmaxf(fmaxf(fmaxf(r0, r1), fmaxf(r2, r3)), r4);
            int sh2 = (m > 0.0f)
                        ? (187 - ((__float_as_int(m) >> 23) & 0xFF)) : 0;
            r0 = ldexpf(r0, sh2); r1 = ldexpf(r1, sh2); r2 = ldexpf(r2, sh2);
            r3 = ldexpf(r3, sh2); r4 = ldexpf(r4, sh2);
            E -= sh2;
          }
        }
      }
    } else {
      // -------- producers: fill phase p+2 with PROBS --------
      const int ptid = tid - 64;
      const int t0 = 65 + 32 * p;
      if (t0 < T_DIM) {
        #pragma unroll
        for (int i = 0; i < 6; ++i) {
          const int task = i * 192 + ptid;         // 32 rows x 32 float4
          if (task < 1024) {
            const int row = task >> 5;
            const int c4  = task & 31;
            const int t   = t0 + row;
            if (t < T_DIM) {
              const float4 v = *(const float4*)(base + (size_t)t * RSTR + c4 * 4);
              float4 w;
              w.x = __builtin_amdgcn_exp2f(v.x * LOG2E);
              w.y = __builtin_amdgcn_exp2f(v.y * LOG2E);
              w.z = __builtin_amdgcn_exp2f(v.z * LOG2E);
              w.w = __builtin_amdgcn_exp2f(v.w * LOG2E);
              *(float4*)&pf[row * C_DIM + c4 * 4] = w;
              if (t < Tb) {
                float s = v.x + v.y + v.z + v.w;
                if (c4 == 0) s -= v.x;
                klacc += s;
              }
            }
          }
        }
      }
    }
    __syncthreads();
    float* tmp = pc; pc = pn; pn = pf; pf = tmp;   // rotate ring
  }

  // ---------------- epilogue ----------------
  if (tid < 64) {
    const int l = tid;
    const float Ef = (float)E;                     // |E| <~ 5e4: exact
    als[4 * l + 0] = __builtin_amdgcn_logf(r0) + Ef;
    als[4 * l + 1] = __builtin_amdgcn_logf(r1) + Ef;
    als[4 * l + 2] = __builtin_amdgcn_logf(r2) + Ef;
    als[4 * l + 3] = __builtin_amdgcn_logf(r3) + Ef;
    if (l == 63) als[256] = __builtin_amdgcn_logf(r4) + Ef;
  } else {
    float tot = klacc;
    tot += __shfl_xor(tot, 1, 64);
    tot += __shfl_xor(tot, 2, 64);
    tot += __shfl_xor(tot, 4, 64);
    tot += __shfl_xor(tot, 8, 64);
    tot += __shfl_xor(tot, 16, 64);
    tot += __shfl_xor(tot, 32, 64);
    if ((tid & 63) == 0) klred[(tid >> 6) - 1] = tot;
  }
  __syncthreads();
  if (tid == 0) {
    const int Lt = tg_len[b];
    const float xa = als[2 * Lt], xb = als[2 * Lt - 1];  // log2 domain
    const float mm = fmaxf(xa, xb);
    float loss = 0.f;
    if (mm > -1e30f) {
      loss = -((mm + __builtin_amdgcn_logf(
          __builtin_amdgcn_exp2f(xa - mm) + __builtin_amdgcn_exp2f(xb - mm))) * LN2);
    }
    ws[b] = loss;                                  // zero_infinity: loss 0
    ws[B_DIM + b] = klred[0] + klred[1] + klred[2];
  }
}

__global__ __launch_bounds__(128) void ctc_finalize_kernel(
    const float* __restrict__ ws, const int* __restrict__ in_len,
    float* __restrict__ out)
{
  __shared__ float red[128];
  const int tid = threadIdx.x;
  float v = 0.0f;
  if (tid < B_DIM) {
    const float ctc  = ws[tid];
    const float kls  = ws[B_DIM + tid];
    const float u    = 1.0f / (C_DIM - 1);
    const float logu = -4.8441870864585910f;       // log(1/127)
    const float klmean = logu - u * kls / (float)in_len[tid];
    v = (1.0f - SMOOTH) * ctc + SMOOTH * klmean;
  }
  red[tid] = v;
  __syncthreads();
  for (int off = 64; off > 0; off >>= 1) {
    if (tid < off) red[tid] += red[tid + off];
    __syncthreads();
  }
  if (tid == 0) out[0] = red[0] / (float)B_DIM;
}

extern "C" void kernel_launch(void* const* d_in, const int* in_sizes, int n_in,
                              void* d_out, int out_size, void* d_ws, size_t ws_size,
                              hipStream_t stream) {
  const float* lp      = (const float*)d_in[0];
  const int* targets   = (const int*)d_in[1];
  const int* in_len    = (const int*)d_in[2];
  const int* tg_len    = (const int*)d_in[3];
  float* ws  = (float*)d_ws;
  float* out = (float*)d_out;

  hipLaunchKernelGGL(ctc_fused_kernel, dim3(B_DIM), dim3(256), 0, stream,
                     lp, targets, in_len, tg_len, ws);
  hipLaunchKernelGGL(ctc_finalize_kernel, dim3(1), dim3(128), 0, stream,
                     ws, in_len, out);
}

// Round 10
// 156.340 us; speedup vs baseline: 5.3709x; 1.6258x over previous
//
#include <hip/hip_runtime.h>
#include <math.h>

#define T_DIM 2048
#define B_DIM 96
#define C_DIM 128
#define L_DIM 128
#define LOG2E 1.4426950408889634f
#define LN2 0.69314718055994531f
#define SMOOTH 0.1f
#define SENT (-(1 << 30))       // virgin lane frame (f32-exact power of 2)
#define NPH 64                  // 64 phases x 32 steps cover t = 1..2047

// wave shift-right-by-1, 0-fill — the R1/R6/R7/R9-proven helper (float only).
__device__ __forceinline__ float dpp_shr1_f(float x) {
  return __int_as_float(__builtin_amdgcn_update_dpp(
      0, __float_as_int(x), 0x138 /*WAVE_SR1*/, 0xF, 0xF, true));
}

// One CTC step (R9-proven math, unchanged). k_ is a compile-time unroll index.
#define CTC_STEP(kk_) do {                                                   \
  const int k_ = (kk_);                                                      \
  const float pAv = fA[k_ & 3], pBv = fB[k_ & 3], pKv = fK[k_ & 3];          \
  {                                                                          \
    const int kn = k_ + 4;                                                   \
    const float* nr = (kn < 32) ? (pc + kn * C_DIM)                          \
                                : (pn + (kn - 32) * C_DIM);                  \
    fA[k_ & 3] = nr[tgA]; fB[k_ & 3] = nr[tgB]; fK[k_ & 3] = nr[0];          \
  }                                                                          \
  const float r3s = dpp_shr1_f(r3);                                          \
  const int   Es  = (int)dpp_shr1_f((float)E);                               \
  const int   be  = (__float_as_int(r3s) >> 23) & 0xFF;                      \
  int diff = (be - 187) + (Es - E);                                          \
  diff = (__float_as_int(r3s) != 0 && diff > 0) ? diff : 0;                  \
  r0 = ldexpf(r0, -diff); r1 = ldexpf(r1, -diff); r2 = ldexpf(r2, -diff);    \
  r3 = ldexpf(r3, -diff); r4 = ldexpf(r4, -diff);                            \
  E += diff;                                                                 \
  const float d3 = ldexpf(r3s, Es - E);                                      \
  const float n0 = (r0 + d3) * pKv;                                          \
  const float n1 = __builtin_fmaf(skA, d3, r0 + r1) * pAv;                   \
  const float n2 = (r2 + r1) * pKv;                                          \
  const float n3 = __builtin_fmaf(skB, r1, r3 + r2) * pBv;                   \
  const float n4 = (r4 + r3) * pKv;                                          \
  r0 = n0; r1 = n1; r2 = n2; r3 = n3; r4 = n4;                               \
  if ((k_ & 3) == 3) {                                                       \
    const float m = fmaxf(fmaxf(fmaxf(r0, r1), fmaxf(r2, r3)), r4);          \
    const int sh2 = (m > 0.0f)                                               \
                      ? (187 - ((__float_as_int(m) >> 23) & 0xFF)) : 0;      \
    r0 = ldexpf(r0, sh2); r1 = ldexpf(r1, sh2); r2 = ldexpf(r2, sh2);        \
    r3 = ldexpf(r3, sh2); r4 = ldexpf(r4, sh2);                              \
    E -= sh2;                                                                \
  }                                                                          \
} while (0)

// One block (256 thr) per sample b.
//   wave 0   (consumer): CTC alpha recursion (R9 math). Phase body is
//     BRANCH-FREE when all 32 steps are active -> compiler keeps the depth-4
//     LDS pipeline with counted lgkmcnt (no conservative drains at joins).
//   waves1-3 (producer): stream rows coalesced, write p=exp2(lp*log2e) into a
//     triple-buffered LDS ring 2 phases ahead; accumulate KL from raw values.
__global__ __launch_bounds__(256) void ctc_fused_kernel(
    const float* __restrict__ lp, const int* __restrict__ targets,
    const int* __restrict__ in_len, const int* __restrict__ tg_len,
    float* __restrict__ ws)
{
  const int tid = threadIdx.x;
  const int b = blockIdx.x;
  const size_t RSTR = (size_t)B_DIM * C_DIM;       // floats per t-row
  const int Tb = in_len[b];
  const float* base = lp + (size_t)b * C_DIM;

  __shared__ float rows[3][32][C_DIM];             // 48 KB ring of PROBS
  __shared__ float als[257];
  __shared__ float klred[3];

  // consumer state
  int tgA = 0, tgB = 0;
  float skA = 0.f, skB = 0.f;
  float r0 = 0.f, r1 = 0.f, r2 = 0.f, r3 = 0.f, r4 = 0.f;
  int E = SENT;
  float fA[4], fB[4], fK[4];                       // depth-4 LDS pipeline
  float klacc = 0.f;                               // producers only

  if (tid < 64) {
    const int l = tid;
    tgA = targets[b * L_DIM + 2 * l];
    tgB = targets[b * L_DIM + 2 * l + 1];
    skA = (l > 0 && tgA != targets[b * L_DIM + 2 * l - 1]) ? 1.f : 0.f;
    skB = (tgB != tgA) ? 1.f : 0.f;
    if (l == 0) {
      r0 = __builtin_amdgcn_exp2f(base[0]   * LOG2E);
      r1 = __builtin_amdgcn_exp2f(base[tgA] * LOG2E);
      E = 0;
    }
  } else {
    // prefill rows t=1..64 (bufs 0,1) as PROBS; KL for t=0..64 from raw
    const int ptid = tid - 64;                     // 0..191
    #pragma unroll
    for (int i = 0; i < 11; ++i) {
      const int task = i * 192 + ptid;             // 64 rows x 32 float4
      if (task < 2048) {
        const int row = task >> 5;
        const int c4  = task & 31;
        const int t   = 1 + row;
        const float4 v = *(const float4*)(base + (size_t)t * RSTR + c4 * 4);
        float4 w;
        w.x = __builtin_amdgcn_exp2f(v.x * LOG2E);
        w.y = __builtin_amdgcn_exp2f(v.y * LOG2E);
        w.z = __builtin_amdgcn_exp2f(v.z * LOG2E);
        w.w = __builtin_amdgcn_exp2f(v.w * LOG2E);
        *(float4*)&rows[row >> 5][row & 31][c4 * 4] = w;
        if (t < Tb) {
          float s = v.x + v.y + v.z + v.w;
          if (c4 == 0) s -= v.x;
          klacc += s;
        }
      }
    }
    if (ptid < 32 && 0 < Tb) {                     // row 0 KL contribution
      const float4 v = *(const float4*)(base + ptid * 4);
      float s = v.x + v.y + v.z + v.w;
      if (ptid == 0) s -= v.x;
      klacc += s;
    }
  }
  __syncthreads();

  if (tid < 64) {                                  // pipeline prologue
    #pragma unroll
    for (int j = 0; j < 4; ++j) {
      fA[j] = rows[0][j][tgA]; fB[j] = rows[0][j][tgB]; fK[j] = rows[0][j][0];
    }
  }

  float* pc = &rows[0][0][0];
  float* pn = &rows[1][0][0];
  float* pf = &rows[2][0][0];

  for (int p = 0; p < NPH; ++p) {
    if (tid < 64) {
      if (32 * p + 33 <= Tb) {
        // -------- FAST phase: all 32 steps active, branch-free --------
        #pragma unroll
        for (int k = 0; k < 32; ++k) { CTC_STEP(k); }
      } else {
        // -------- tail / short-length phase: per-step guard --------
        #pragma unroll
        for (int k = 0; k < 32; ++k) {
          const int t = 1 + 32 * p + k;
          if (t < Tb) { CTC_STEP(k); }
        }
      }
    } else {
      // -------- producers: fill phase p+2 with PROBS --------
      const int ptid = tid - 64;
      const int t0 = 65 + 32 * p;
      if (t0 < T_DIM) {
        #pragma unroll
        for (int i = 0; i < 6; ++i) {
          const int task = i * 192 + ptid;         // 32 rows x 32 float4
          if (task < 1024) {
            const int row = task >> 5;
            const int c4  = task & 31;
            const int t   = t0 + row;
            if (t < T_DIM) {
              const float4 v = *(const float4*)(base + (size_t)t * RSTR + c4 * 4);
              float4 w;
              w.x = __builtin_amdgcn_exp2f(v.x * LOG2E);
              w.y = __builtin_amdgcn_exp2f(v.y * LOG2E);
              w.z = __builtin_amdgcn_exp2f(v.z * LOG2E);
              w.w = __builtin_amdgcn_exp2f(v.w * LOG2E);
              *(float4*)&pf[row * C_DIM + c4 * 4] = w;
              if (t < Tb) {
                float s = v.x + v.y + v.z + v.w;
                if (c4 == 0) s -= v.x;
                klacc += s;
              }
            }
          }
        }
      }
    }
    __syncthreads();
    float* tmp = pc; pc = pn; pn = pf; pf = tmp;   // rotate ring
  }

  // ---------------- epilogue ----------------
  if (tid < 64) {
    const int l = tid;
    const float Ef = (float)E;                     // |E| <~ 5e4: exact
    als[4 * l + 0] = __builtin_amdgcn_logf(r0) + Ef;
    als[4 * l + 1] = __builtin_amdgcn_logf(r1) + Ef;
    als[4 * l + 2] = __builtin_amdgcn_logf(r2) + Ef;
    als[4 * l + 3] = __builtin_amdgcn_logf(r3) + Ef;
    if (l == 63) als[256] = __builtin_amdgcn_logf(r4) + Ef;
  } else {
    float tot = klacc;
    tot += __shfl_xor(tot, 1, 64);
    tot += __shfl_xor(tot, 2, 64);
    tot += __shfl_xor(tot, 4, 64);
    tot += __shfl_xor(tot, 8, 64);
    tot += __shfl_xor(tot, 16, 64);
    tot += __shfl_xor(tot, 32, 64);
    if ((tid & 63) == 0) klred[(tid >> 6) - 1] = tot;
  }
  __syncthreads();
  if (tid == 0) {
    const int Lt = tg_len[b];
    const float xa = als[2 * Lt], xb = als[2 * Lt - 1];  // log2 domain
    const float mm = fmaxf(xa, xb);
    float loss = 0.f;
    if (mm > -1e30f) {
      loss = -((mm + __builtin_amdgcn_logf(
          __builtin_amdgcn_exp2f(xa - mm) + __builtin_amdgcn_exp2f(xb - mm))) * LN2);
    }
    ws[b] = loss;                                  // zero_infinity: loss 0
    ws[B_DIM + b] = klred[0] + klred[1] + klred[2];
  }
}

__global__ __launch_bounds__(128) void ctc_finalize_kernel(
    const float* __restrict__ ws, const int* __restrict__ in_len,
    float* __restrict__ out)
{
  __shared__ float red[128];
  const int tid = threadIdx.x;
  float v = 0.0f;
  if (tid < B_DIM) {
    const float ctc  = ws[tid];
    const float kls  = ws[B_DIM + tid];
    const float u    = 1.0f / (C_DIM - 1);
    const float logu = -4.8441870864585910f;       // log(1/127)
    const float klmean = logu - u * kls / (float)in_len[tid];
    v = (1.0f - SMOOTH) * ctc + SMOOTH * klmean;
  }
  red[tid] = v;
  __syncthreads();
  for (int off = 64; off > 0; off >>= 1) {
    if (tid < off) red[tid] += red[tid + off];
    __syncthreads();
  }
  if (tid == 0) out[0] = red[0] / (float)B_DIM;
}

extern "C" void kernel_launch(void* const* d_in, const int* in_sizes, int n_in,
                              void* d_out, int out_size, void* d_ws, size_t ws_size,
                              hipStream_t stream) {
  const float* lp      = (const float*)d_in[0];
  const int* targets   = (const int*)d_in[1];
  const int* in_len    = (const int*)d_in[2];
  const int* tg_len    = (const int*)d_in[3];
  float* ws  = (float*)d_ws;
  float* out = (float*)d_out;

  hipLaunchKernelGGL(ctc_fused_kernel, dim3(B_DIM), dim3(256), 0, stream,
                     lp, targets, in_len, tg_len, ws);
  hipLaunchKernelGGL(ctc_finalize_kernel, dim3(1), dim3(128), 0, stream,
                     ws, in_len, out);
}